// Round 11
// baseline (379.222 us; speedup 1.0000x reference)
//
#include <hip/hip_runtime.h>
#include <hip/hip_bf16.h>

// MultiheadAttention: x[4,2048,1024] fp32 -> out fp32. Internal bf16 MFMA.
// R11: (1) revert R10 ones-MFMA rsum (regressed: MFMA-pipe contention) to
// plain adds; (2) attn 128-key tiles — same bytes/exp, half the barriers;
// (3) gemm BK=64 — 16 K-iters, half the barrier drains (m97-plateau is
// barrier-cadence-bound at short K). XOR swizzles re-derived, 2-way max.

#define DIM  1024
#define SEQ  2048
#define BATCH 4
#define NH   16
#define HD   64

typedef __bf16 bf16x8 __attribute__((ext_vector_type(8)));
typedef short  s16x4  __attribute__((ext_vector_type(4)));
typedef float  f32x4  __attribute__((ext_vector_type(4)));
typedef unsigned int uint4v __attribute__((ext_vector_type(4)));

static __device__ __forceinline__ f32x4 mfma16(s16x4 a, s16x4 b, f32x4 c) {
    return __builtin_amdgcn_mfma_f32_16x16x16bf16_1k(a, b, c, 0, 0, 0);
}

static __device__ __forceinline__ unsigned short f2b(float f) {
    __bf16 h = (__bf16)f;                      // RNE convert
    return __builtin_bit_cast(unsigned short, h);
}

static __device__ __forceinline__ void load_lds16(const unsigned short* g,
                                                  unsigned short* l) {
    __builtin_amdgcn_global_load_lds(
        (const __attribute__((address_space(1))) void*)g,
        (__attribute__((address_space(3))) void*)l, 16, 0, 0);
}

// ---------------------------------------------------------------------------
// Kernel A: x fp32 -> bf16. 8,388,608 elems -> 4096 blocks.
// ---------------------------------------------------------------------------
__global__ __launch_bounds__(256) void cvt_x_k(const float* __restrict__ x,
                                               unsigned short* __restrict__ xb) {
    size_t i = ((size_t)blockIdx.x * 256 + threadIdx.x) * 8;
    const f32x4* s = (const f32x4*)(x + i);
    f32x4 a0 = s[0], a1 = s[1];
    bf16x8 v;
    for (int j = 0; j < 4; j++) { v[j] = (__bf16)a0[j]; v[4 + j] = (__bf16)a1[j]; }
    *(bf16x8*)(xb + i) = v;
}

// ---------------------------------------------------------------------------
// Kernel 0: Wt[n][k] = bf16(W[k][n]) for z = 0,1,2 (Wq,Wk,Wv). fp32 input.
// ---------------------------------------------------------------------------
__global__ void transpose_w_k(const float* __restrict__ Wq,
                              const float* __restrict__ Wk,
                              const float* __restrict__ Wv,
                              unsigned short* __restrict__ Wt) {
    __shared__ unsigned short t[32][33];
    int z = blockIdx.z;
    const float* W = (z == 0) ? Wq : (z == 1) ? Wk : Wv;
    unsigned short* o = Wt + (size_t)z * DIM * DIM;
    int tx = threadIdx.x;
    int n0 = blockIdx.x * 32, k0 = blockIdx.y * 32;
    for (int j = threadIdx.y; j < 32; j += 8)
        t[j][tx] = f2b(W[(size_t)(k0 + j) * DIM + n0 + tx]);
    __syncthreads();
    for (int j = threadIdx.y; j < 32; j += 8)
        o[(size_t)(n0 + j) * DIM + k0 + tx] = t[tx][j];
}

// ---------------------------------------------------------------------------
// Kernel 1: fused QKV projection. grid (8, 32, 3), block 512 (8 waves).
// 256x128 tile, BK=64 (16 K-iters). global_load_lds staging, XOR swizzle
// chunk' = chunk ^ (row&7) over 8-chunk (128B) rows; reads 2-way max.
// z=0 -> Q scaled log2e/8, z=1 -> K, z=2 -> V^T via per-wave LDS transpose.
// ---------------------------------------------------------------------------
__global__ __launch_bounds__(512) void qkv_gemm_k(
    const unsigned short* __restrict__ xb,
    const unsigned short* __restrict__ WtBase,
    const float* __restrict__ bq,
    const float* __restrict__ bk,
    const float* __restrict__ bv,
    unsigned short* __restrict__ Qo,
    unsigned short* __restrict__ Ko,
    unsigned short* __restrict__ Vto) {
    __shared__ __align__(16) unsigned short As[256 * 64];   // 32 KB, NO pad
    __shared__ __align__(16) unsigned short Bs[128 * 64];   // 16 KB
    int tid = threadIdx.x, wave = tid >> 6, lane = tid & 63;
    int quad = lane >> 4, lc = lane & 15;
    int m0 = blockIdx.y * 256, n0 = blockIdx.x * 128;
    int z = blockIdx.z;
    const unsigned short* Wt = WtBase + (size_t)z * DIM * DIM;
    int wm = (wave >> 1) * 64, wn = (wave & 1) * 64;

    // A: 2048 chunks (4/thread), B: 1024 chunks (2/thread); row=c>>3, cc=c&7,
    // global source chunk = cc ^ (row&7)
    int swzlo = lc & 7;

    f32x4 acc[4][4] = {};

    for (int k0 = 0; k0 < DIM; k0 += 64) {
        __syncthreads();
        #pragma unroll
        for (int p = 0; p < 4; p++) {
            int c = tid + p * 512, r = c >> 3, cc = (c & 7) ^ (r & 7);
            load_lds16(xb + (size_t)(m0 + r) * DIM + k0 + cc * 8, &As[c * 8]);
        }
        #pragma unroll
        for (int p = 0; p < 2; p++) {
            int c = tid + p * 512, r = c >> 3, cc = (c & 7) ^ (r & 7);
            load_lds16(Wt + (size_t)(n0 + r) * DIM + k0 + cc * 8, &Bs[c * 8]);
        }
        __syncthreads();
        #pragma unroll
        for (int kk = 0; kk < 2; kk++) {
            int off = ((kk * 4 + quad) ^ swzlo) * 8;
            bf16x8 af[4], bfr[4];
            for (int mt = 0; mt < 4; mt++)
                af[mt] = *(const bf16x8*)&As[(wm + mt * 16 + lc) * 64 + off];
            for (int nt = 0; nt < 4; nt++)
                bfr[nt] = *(const bf16x8*)&Bs[(wn + nt * 16 + lc) * 64 + off];
            for (int mt = 0; mt < 4; mt++)
                for (int nt = 0; nt < 4; nt++)
                    acc[mt][nt] = __builtin_amdgcn_mfma_f32_16x16x32_bf16(
                        af[mt], bfr[nt], acc[mt][nt], 0, 0, 0);
        }
    }

    const float* bias = (z == 0) ? bq : (z == 1) ? bk : bv;
    float scale = (z == 0) ? 0.18033688011112042f : 1.0f;  // (1/8)*log2(e)

    if (z != 2) {
        for (int nt = 0; nt < 4; nt++) {
            int n = n0 + wn + nt * 16 + lc;
            float bvl = bias[n];
            int h = n >> 6, d = n & 63;
            for (int mt = 0; mt < 4; mt++) {
                for (int r = 0; r < 4; r++) {
                    int m = m0 + wm + mt * 16 + quad * 4 + r;
                    int b = m >> 11, s = m & 2047;
                    unsigned short ub = f2b((acc[mt][nt][r] + bvl) * scale);
                    if (z == 0)
                        Qo[((size_t)(b * NH + h) * SEQ + s) * HD + d] = ub;
                    else
                        Ko[((size_t)(b * NH + h) * SEQ + s) * HD + d] = ub;
                }
            }
        }
    } else {
        // V^T: per-wave LDS transpose (16 m x 64 n slices), coalesced stores.
        __syncthreads();  // all waves done reading As/Bs
        unsigned short* T = As + wave * 1024;   // 64 n-rows x 16 m, 2 KB/wave
        int h = (n0 + wn) >> 6;                 // 64-aligned, single head/wave
        int d = lane;                           // 0..63 within head
        for (int mt = 0; mt < 4; mt++) {
            for (int nt = 0; nt < 4; nt++) {
                int n = n0 + wn + nt * 16 + lc;
                float bvl = bias[n];
                s16x4 v4;
                for (int r = 0; r < 4; r++)
                    v4[r] = (short)f2b(acc[mt][nt][r] + bvl);
                *(s16x4*)&T[(nt * 16 + lc) * 16 + quad * 4] = v4;  // ds_write_b64
            }
            int s_base = m0 + wm + mt * 16;
            int b = s_base >> 11, sl = s_base & 2047;
            unsigned short* dst =
                Vto + ((size_t)(b * NH + h) * HD + d) * SEQ + sl;
            uint4v t0 = *(const uint4v*)&T[d * 16];
            uint4v t1 = *(const uint4v*)&T[d * 16 + 8];
            *(uint4v*)&dst[0] = t0;
            *(uint4v*)&dst[8] = t1;
        }
    }
}

// ---------------------------------------------------------------------------
// Kernel 2: flash attention v6 (t-split, 128-key tiles). grid (32,16,4).
// Wave w handles all 64 q for t in [t0+w*32, t0+w*32+32), two 16-key slices.
// rsum: plain per-lane adds (R9 scheme; R10 ones-MFMA regressed).
// ---------------------------------------------------------------------------
__global__ __launch_bounds__(256) void attn_k(
    const unsigned short* __restrict__ Q,
    const unsigned short* __restrict__ K,
    const unsigned short* __restrict__ Vt,
    float* __restrict__ out) {
    constexpr int LDK = 72;    // Ks rows 144B
    constexpr int LDV = 136;   // Vs rows 272B (128 + 8 pad; 272%128=16 -> 2-way)
    __shared__ __align__(16) unsigned short Ks[128 * LDK];  // 18432 B
    __shared__ __align__(16) unsigned short Vs[64 * LDV];   // 17408 B

    int tid = threadIdx.x, wave = tid >> 6, lane = tid & 63;
    int quad = lane >> 4, lc = lane & 15;
    int b = blockIdx.z, h = blockIdx.y, qt = blockIdx.x;
    int bh = b * NH + h;
    const unsigned short* Qg = Q + ((size_t)bh * SEQ + qt * 64) * HD;
    const unsigned short* Kg = K + (size_t)bh * SEQ * HD;
    const unsigned short* Vg = Vt + (size_t)bh * HD * SEQ;

    // stage Q (64x64) through Ks; pull all 4 q-group B-frags to registers
    for (int p = 0; p < 2; p++) {
        int c = tid + p * 256;
        int row = c >> 3, cc = c & 7;
        *(uint4v*)&Ks[row * LDK + cc * 8] = *(const uint4v*)&Qg[c * 8];
    }
    __syncthreads();
    bf16x8 qf[4][2];  // [g][ks]: B[k=d=ks*32+quad*8+j][n=q=g*16+lc]
    #pragma unroll
    for (int g = 0; g < 4; g++)
        #pragma unroll
        for (int ks = 0; ks < 2; ks++)
            qf[g][ks] = *(const bf16x8*)&Ks[(g * 16 + lc) * LDK + ks * 32 + quad * 8];

    f32x4 o[4][4] = {};   // [dt][g]: O^T[d=dt*16+quad*4+r][q=g*16+lc]
    float rsum[4] = {};

    for (int t0 = 0; t0 < SEQ; t0 += 128) {
        __syncthreads();
        #pragma unroll
        for (int p = 0; p < 4; p++) {
            int c = tid + p * 256;                 // 0..1023
            int row = c >> 3, cc = c & 7;          // K: 128 t-rows x 8 chunks
            *(uint4v*)&Ks[row * LDK + cc * 8] =
                *(const uint4v*)&Kg[(size_t)t0 * HD + c * 8];
            int rv = c >> 4, cv = c & 15;          // V: 64 d-rows x 16 chunks
            *(uint4v*)&Vs[rv * LDV + cv * 8] =
                *(const uint4v*)&Vg[(size_t)rv * SEQ + t0 + cv * 8];
        }
        __syncthreads();

        #pragma unroll
        for (int u = 0; u < 2; u++) {
            int tw = wave * 32 + u * 16;
            f32x4 sc[4] = {};
            #pragma unroll
            for (int ks = 0; ks < 2; ks++) {
                bf16x8 kf = *(const bf16x8*)&Ks[(tw + lc) * LDK + ks * 32 + quad * 8];
                #pragma unroll
                for (int g = 0; g < 4; g++)
                    sc[g] = __builtin_amdgcn_mfma_f32_16x16x32_bf16(
                        kf, qf[g][ks], sc[g], 0, 0, 0);
            }

            s16x4 pf[4];
            #pragma unroll
            for (int g = 0; g < 4; g++) {
                float p0 = __builtin_amdgcn_exp2f(sc[g][0]);
                float p1 = __builtin_amdgcn_exp2f(sc[g][1]);
                float p2 = __builtin_amdgcn_exp2f(sc[g][2]);
                float p3 = __builtin_amdgcn_exp2f(sc[g][3]);
                rsum[g] += (p0 + p1) + (p2 + p3);
                pf[g][0] = (short)f2b(p0); pf[g][1] = (short)f2b(p1);
                pf[g][2] = (short)f2b(p2); pf[g][3] = (short)f2b(p3);
            }

            #pragma unroll
            for (int dt = 0; dt < 4; dt++) {
                s16x4 vf = *(const s16x4*)&Vs[(dt * 16 + lc) * LDV + tw + quad * 4];
                #pragma unroll
                for (int g = 0; g < 4; g++)
                    o[dt][g] = mfma16(vf, pf[g], o[dt][g]);
            }
        }
    }

    // rsum: sum the 4 quads (t-slices within wave)
    #pragma unroll
    for (int g = 0; g < 4; g++) {
        rsum[g] += __shfl_xor(rsum[g], 16);
        rsum[g] += __shfl_xor(rsum[g], 32);
    }

    __syncthreads();  // all waves done with Ks/Vs
    float* OredF = (float*)Ks;            // [4w][64q][16dd] = 16384 B (fits)
    float* rsArr = (float*)Ks + 4096;     // [4w][64q] = 1024 B
    if (lane < 16)
        #pragma unroll
        for (int g = 0; g < 4; g++)
            rsArr[wave * 64 + g * 16 + lane] = rsum[g];

    int q = tid >> 2, cs = tid & 3;
    float inv = 0.0f;
    float* orow = out + ((size_t)b * SEQ + qt * 64 + q) * DIM + h * HD;
    #pragma unroll
    for (int dt = 0; dt < 4; dt++) {
        #pragma unroll
        for (int g = 0; g < 4; g++)
            *(f32x4*)&OredF[wave * 1024 + (g * 16 + lc) * 16 + quad * 4] = o[dt][g];
        __syncthreads();
        if (dt == 0)
            inv = 1.0f / (rsArr[q] + rsArr[64 + q] + rsArr[128 + q] + rsArr[192 + q]);
        f32x4 s = *(const f32x4*)&OredF[q * 16 + cs * 4];
        #pragma unroll
        for (int w = 1; w < 4; w++)
            s += *(const f32x4*)&OredF[w * 1024 + q * 16 + cs * 4];
        s *= inv;
        *(f32x4*)&orow[dt * 16 + cs * 4] = s;
        __syncthreads();
    }
}

// ---------------------------------------------------------------------------
extern "C" void kernel_launch(void* const* d_in, const int* in_sizes, int n_in,
                              void* d_out, int out_size, void* d_ws, size_t ws_size,
                              hipStream_t stream) {
    (void)in_sizes; (void)n_in; (void)out_size; (void)ws_size;
    const float* x  = (const float*)d_in[0];
    const float* Wq = (const float*)d_in[1];
    const float* bq = (const float*)d_in[2];
    const float* Wk = (const float*)d_in[3];
    const float* bk = (const float*)d_in[4];
    const float* Wv = (const float*)d_in[5];
    const float* bv = (const float*)d_in[6];

    char* ws = (char*)d_ws;
    unsigned short* Wt = (unsigned short*)ws;                             // 6 MB
    unsigned short* Qb = (unsigned short*)(ws + (size_t)6 * 1024 * 1024);
    unsigned short* Kb = Qb + (size_t)BATCH * NH * SEQ * HD;
    unsigned short* Vb = Kb + (size_t)BATCH * NH * SEQ * HD;
    unsigned short* xb = (unsigned short*)d_out;  // scratch; attn overwrites

    cvt_x_k<<<dim3(4096), dim3(256), 0, stream>>>(x, xb);
    transpose_w_k<<<dim3(32, 32, 3), dim3(32, 8), 0, stream>>>(Wq, Wk, Wv, Wt);
    qkv_gemm_k<<<dim3(8, 32, 3), dim3(512), 0, stream>>>(xb, Wt, bq, bk, bv, Qb, Kb, Vb);
    attn_k<<<dim3(32, NH, BATCH), dim3(256), 0, stream>>>(Qb, Kb, Vb, (float*)d_out);
}

// Round 12
// 311.791 us; speedup vs baseline: 1.2163x; 1.2163x over previous
//
#include <hip/hip_runtime.h>
#include <hip/hip_bf16.h>

// MultiheadAttention: x[4,2048,1024] fp32 -> out fp32. Internal bf16 MFMA.
// R12: revert attn to R8 structure (64-key tiles, plain rsum — R11's 128-key
// tile halved blocks/CU and collapsed VALUBusy 61->33%). Keep R11 gemm
// (256x128, BK=64). New: attn K/V staging via global_load_lds + XOR swizzle
// (gemm-verified pattern) — kills the VGPR round-trip + staging VALU.

#define DIM  1024
#define SEQ  2048
#define BATCH 4
#define NH   16
#define HD   64

typedef __bf16 bf16x8 __attribute__((ext_vector_type(8)));
typedef short  s16x4  __attribute__((ext_vector_type(4)));
typedef float  f32x4  __attribute__((ext_vector_type(4)));
typedef unsigned int uint4v __attribute__((ext_vector_type(4)));

static __device__ __forceinline__ f32x4 mfma16(s16x4 a, s16x4 b, f32x4 c) {
    return __builtin_amdgcn_mfma_f32_16x16x16bf16_1k(a, b, c, 0, 0, 0);
}

static __device__ __forceinline__ unsigned short f2b(float f) {
    __bf16 h = (__bf16)f;                      // RNE convert
    return __builtin_bit_cast(unsigned short, h);
}

static __device__ __forceinline__ void load_lds16(const unsigned short* g,
                                                  unsigned short* l) {
    __builtin_amdgcn_global_load_lds(
        (const __attribute__((address_space(1))) void*)g,
        (__attribute__((address_space(3))) void*)l, 16, 0, 0);
}

// ---------------------------------------------------------------------------
// Kernel A: x fp32 -> bf16. 8,388,608 elems -> 4096 blocks.
// ---------------------------------------------------------------------------
__global__ __launch_bounds__(256) void cvt_x_k(const float* __restrict__ x,
                                               unsigned short* __restrict__ xb) {
    size_t i = ((size_t)blockIdx.x * 256 + threadIdx.x) * 8;
    const f32x4* s = (const f32x4*)(x + i);
    f32x4 a0 = s[0], a1 = s[1];
    bf16x8 v;
    for (int j = 0; j < 4; j++) { v[j] = (__bf16)a0[j]; v[4 + j] = (__bf16)a1[j]; }
    *(bf16x8*)(xb + i) = v;
}

// ---------------------------------------------------------------------------
// Kernel 0: Wt[n][k] = bf16(W[k][n]) for z = 0,1,2 (Wq,Wk,Wv). fp32 input.
// ---------------------------------------------------------------------------
__global__ void transpose_w_k(const float* __restrict__ Wq,
                              const float* __restrict__ Wk,
                              const float* __restrict__ Wv,
                              unsigned short* __restrict__ Wt) {
    __shared__ unsigned short t[32][33];
    int z = blockIdx.z;
    const float* W = (z == 0) ? Wq : (z == 1) ? Wk : Wv;
    unsigned short* o = Wt + (size_t)z * DIM * DIM;
    int tx = threadIdx.x;
    int n0 = blockIdx.x * 32, k0 = blockIdx.y * 32;
    for (int j = threadIdx.y; j < 32; j += 8)
        t[j][tx] = f2b(W[(size_t)(k0 + j) * DIM + n0 + tx]);
    __syncthreads();
    for (int j = threadIdx.y; j < 32; j += 8)
        o[(size_t)(n0 + j) * DIM + k0 + tx] = t[tx][j];
}

// ---------------------------------------------------------------------------
// Kernel 1: fused QKV projection (R11, unchanged). grid (8, 32, 3), block 512.
// 256x128 tile, BK=64. global_load_lds + XOR swizzle chunk^=(row&7).
// z=0 -> Q scaled log2e/8, z=1 -> K, z=2 -> V^T via per-wave LDS transpose.
// ---------------------------------------------------------------------------
__global__ __launch_bounds__(512) void qkv_gemm_k(
    const unsigned short* __restrict__ xb,
    const unsigned short* __restrict__ WtBase,
    const float* __restrict__ bq,
    const float* __restrict__ bk,
    const float* __restrict__ bv,
    unsigned short* __restrict__ Qo,
    unsigned short* __restrict__ Ko,
    unsigned short* __restrict__ Vto) {
    __shared__ __align__(16) unsigned short As[256 * 64];   // 32 KB, NO pad
    __shared__ __align__(16) unsigned short Bs[128 * 64];   // 16 KB
    int tid = threadIdx.x, wave = tid >> 6, lane = tid & 63;
    int quad = lane >> 4, lc = lane & 15;
    int m0 = blockIdx.y * 256, n0 = blockIdx.x * 128;
    int z = blockIdx.z;
    const unsigned short* Wt = WtBase + (size_t)z * DIM * DIM;
    int wm = (wave >> 1) * 64, wn = (wave & 1) * 64;
    int swzlo = lc & 7;

    f32x4 acc[4][4] = {};

    for (int k0 = 0; k0 < DIM; k0 += 64) {
        __syncthreads();
        #pragma unroll
        for (int p = 0; p < 4; p++) {
            int c = tid + p * 512, r = c >> 3, cc = (c & 7) ^ (r & 7);
            load_lds16(xb + (size_t)(m0 + r) * DIM + k0 + cc * 8, &As[c * 8]);
        }
        #pragma unroll
        for (int p = 0; p < 2; p++) {
            int c = tid + p * 512, r = c >> 3, cc = (c & 7) ^ (r & 7);
            load_lds16(Wt + (size_t)(n0 + r) * DIM + k0 + cc * 8, &Bs[c * 8]);
        }
        __syncthreads();
        #pragma unroll
        for (int kk = 0; kk < 2; kk++) {
            int off = ((kk * 4 + quad) ^ swzlo) * 8;
            bf16x8 af[4], bfr[4];
            for (int mt = 0; mt < 4; mt++)
                af[mt] = *(const bf16x8*)&As[(wm + mt * 16 + lc) * 64 + off];
            for (int nt = 0; nt < 4; nt++)
                bfr[nt] = *(const bf16x8*)&Bs[(wn + nt * 16 + lc) * 64 + off];
            for (int mt = 0; mt < 4; mt++)
                for (int nt = 0; nt < 4; nt++)
                    acc[mt][nt] = __builtin_amdgcn_mfma_f32_16x16x32_bf16(
                        af[mt], bfr[nt], acc[mt][nt], 0, 0, 0);
        }
    }

    const float* bias = (z == 0) ? bq : (z == 1) ? bk : bv;
    float scale = (z == 0) ? 0.18033688011112042f : 1.0f;  // (1/8)*log2(e)

    if (z != 2) {
        for (int nt = 0; nt < 4; nt++) {
            int n = n0 + wn + nt * 16 + lc;
            float bvl = bias[n];
            int h = n >> 6, d = n & 63;
            for (int mt = 0; mt < 4; mt++) {
                for (int r = 0; r < 4; r++) {
                    int m = m0 + wm + mt * 16 + quad * 4 + r;
                    int b = m >> 11, s = m & 2047;
                    unsigned short ub = f2b((acc[mt][nt][r] + bvl) * scale);
                    if (z == 0)
                        Qo[((size_t)(b * NH + h) * SEQ + s) * HD + d] = ub;
                    else
                        Ko[((size_t)(b * NH + h) * SEQ + s) * HD + d] = ub;
                }
            }
        }
    } else {
        // V^T: per-wave LDS transpose (16 m x 64 n slices), coalesced stores.
        __syncthreads();
        unsigned short* T = As + wave * 1024;
        int h = (n0 + wn) >> 6;
        int d = lane;
        for (int mt = 0; mt < 4; mt++) {
            for (int nt = 0; nt < 4; nt++) {
                int n = n0 + wn + nt * 16 + lc;
                float bvl = bias[n];
                s16x4 v4;
                for (int r = 0; r < 4; r++)
                    v4[r] = (short)f2b(acc[mt][nt][r] + bvl);
                *(s16x4*)&T[(nt * 16 + lc) * 16 + quad * 4] = v4;
            }
            int s_base = m0 + wm + mt * 16;
            int b = s_base >> 11, sl = s_base & 2047;
            unsigned short* dst =
                Vto + ((size_t)(b * NH + h) * HD + d) * SEQ + sl;
            uint4v t0 = *(const uint4v*)&T[d * 16];
            uint4v t1 = *(const uint4v*)&T[d * 16 + 8];
            *(uint4v*)&dst[0] = t0;
            *(uint4v*)&dst[8] = t1;
        }
    }
}

// ---------------------------------------------------------------------------
// Kernel 2: flash attention v7 (R8 structure + global_load_lds staging).
// grid (32,16,4), block 256 (4 waves). Wave w: all 64 q x 16 t per 64-key
// tile. Ks/Vs unpadded 64x64, XOR swizzle chunk^=(row&7); kf/vf reads 2-way.
// ---------------------------------------------------------------------------
__global__ __launch_bounds__(256) void attn_k(
    const unsigned short* __restrict__ Q,
    const unsigned short* __restrict__ K,
    const unsigned short* __restrict__ Vt,
    float* __restrict__ out) {
    __shared__ __align__(16) unsigned char smem[17408];
    unsigned short* Ks = (unsigned short*)smem;            // 8192 B (64x64)
    unsigned short* Vs = (unsigned short*)(smem + 8192);   // 8192 B (64x64)

    int tid = threadIdx.x, wave = tid >> 6, lane = tid & 63;
    int quad = lane >> 4, lc = lane & 15;
    int w16 = wave * 16;
    int b = blockIdx.z, h = blockIdx.y, qt = blockIdx.x;
    int bh = b * NH + h;
    const unsigned short* Qg = Q + ((size_t)bh * SEQ + qt * 64) * HD;
    const unsigned short* Kg = K + (size_t)bh * SEQ * HD;
    const unsigned short* Vg = Vt + (size_t)bh * HD * SEQ;

    // stage Q (64x64, plain layout) through Ks; one-time frag pull
    for (int p = 0; p < 2; p++) {
        int c = tid + p * 256;
        *(uint4v*)&Ks[c * 8] = *(const uint4v*)&Qg[c * 8];
    }
    __syncthreads();
    bf16x8 qf[4][2];  // [g][ks]: B[k=d=ks*32+quad*8+j][n=q=g*16+lc]
    #pragma unroll
    for (int g = 0; g < 4; g++)
        #pragma unroll
        for (int ks = 0; ks < 2; ks++)
            qf[g][ks] = *(const bf16x8*)&Ks[(g * 16 + lc) * 64 + ks * 32 + quad * 8];

    f32x4 o[4][4] = {};   // [dt][g]: O^T[d=dt*16+quad*4+r][q=g*16+lc]
    float rsum[4] = {};
    int swzlo = lc & 7;

    for (int t0 = 0; t0 < SEQ; t0 += 64) {
        __syncthreads();
        #pragma unroll
        for (int p = 0; p < 2; p++) {
            int c = tid + p * 256;                 // 0..511
            int r = c >> 3, cc = (c & 7) ^ (r & 7);
            load_lds16(Kg + (size_t)(t0 + r) * HD + cc * 8, &Ks[c * 8]);
            load_lds16(Vg + (size_t)r * SEQ + t0 + cc * 8, &Vs[c * 8]);
        }
        __syncthreads();

        // scores: A = K[t=w16+lc][d], global chunk ks*4+quad at swizzled slot
        f32x4 sc[4] = {};
        #pragma unroll
        for (int ks = 0; ks < 2; ks++) {
            bf16x8 kf = *(const bf16x8*)&Ks[(w16 + lc) * 64 + (((ks << 2) + quad) ^ swzlo) * 8];
            #pragma unroll
            for (int g = 0; g < 4; g++)
                sc[g] = __builtin_amdgcn_mfma_f32_16x16x32_bf16(
                    kf, qf[g][ks], sc[g], 0, 0, 0);
        }

        s16x4 pf[4];
        #pragma unroll
        for (int g = 0; g < 4; g++) {
            float p0 = __builtin_amdgcn_exp2f(sc[g][0]);
            float p1 = __builtin_amdgcn_exp2f(sc[g][1]);
            float p2 = __builtin_amdgcn_exp2f(sc[g][2]);
            float p3 = __builtin_amdgcn_exp2f(sc[g][3]);
            rsum[g] += (p0 + p1) + (p2 + p3);
            pf[g][0] = (short)f2b(p0); pf[g][1] = (short)f2b(p1);
            pf[g][2] = (short)f2b(p2); pf[g][3] = (short)f2b(p3);
        }

        // PV: A = V^T[d=dt*16+lc][t=w16+quad*4+j]; global chunk 2w+(quad>>1),
        // +4 elems if quad odd, at swizzled slot
        #pragma unroll
        for (int dt = 0; dt < 4; dt++) {
            s16x4 vf = *(const s16x4*)&Vs[(dt * 16 + lc) * 64 +
                (((wave << 1) + (quad >> 1)) ^ swzlo) * 8 + (quad & 1) * 4];
            #pragma unroll
            for (int g = 0; g < 4; g++)
                o[dt][g] = mfma16(vf, pf[g], o[dt][g]);
        }
    }

    #pragma unroll
    for (int g = 0; g < 4; g++) {
        rsum[g] += __shfl_xor(rsum[g], 16);
        rsum[g] += __shfl_xor(rsum[g], 32);
    }

    __syncthreads();  // all waves done with Ks/Vs
    float* OredF = (float*)smem;             // [4w][64q][16dd] = 16384 B
    float* rsArr = (float*)(smem + 16384);   // [4w][64q] = 1024 B
    if (lane < 16)
        #pragma unroll
        for (int g = 0; g < 4; g++)
            rsArr[wave * 64 + g * 16 + lane] = rsum[g];

    int q = tid >> 2, cs = tid & 3;
    float inv = 0.0f;
    float* orow = out + ((size_t)b * SEQ + qt * 64 + q) * DIM + h * HD;
    #pragma unroll
    for (int dt = 0; dt < 4; dt++) {
        #pragma unroll
        for (int g = 0; g < 4; g++)
            *(f32x4*)&OredF[wave * 1024 + (g * 16 + lc) * 16 + quad * 4] = o[dt][g];
        __syncthreads();
        if (dt == 0)
            inv = 1.0f / (rsArr[q] + rsArr[64 + q] + rsArr[128 + q] + rsArr[192 + q]);
        f32x4 s = *(const f32x4*)&OredF[q * 16 + cs * 4];
        #pragma unroll
        for (int w = 1; w < 4; w++)
            s += *(const f32x4*)&OredF[w * 1024 + q * 16 + cs * 4];
        s *= inv;
        *(f32x4*)&orow[dt * 16 + cs * 4] = s;
        __syncthreads();
    }
}

// ---------------------------------------------------------------------------
extern "C" void kernel_launch(void* const* d_in, const int* in_sizes, int n_in,
                              void* d_out, int out_size, void* d_ws, size_t ws_size,
                              hipStream_t stream) {
    (void)in_sizes; (void)n_in; (void)out_size; (void)ws_size;
    const float* x  = (const float*)d_in[0];
    const float* Wq = (const float*)d_in[1];
    const float* bq = (const float*)d_in[2];
    const float* Wk = (const float*)d_in[3];
    const float* bk = (const float*)d_in[4];
    const float* Wv = (const float*)d_in[5];
    const float* bv = (const float*)d_in[6];

    char* ws = (char*)d_ws;
    unsigned short* Wt = (unsigned short*)ws;                             // 6 MB
    unsigned short* Qb = (unsigned short*)(ws + (size_t)6 * 1024 * 1024);
    unsigned short* Kb = Qb + (size_t)BATCH * NH * SEQ * HD;
    unsigned short* Vb = Kb + (size_t)BATCH * NH * SEQ * HD;
    unsigned short* xb = (unsigned short*)d_out;  // scratch; attn overwrites

    cvt_x_k<<<dim3(4096), dim3(256), 0, stream>>>(x, xb);
    transpose_w_k<<<dim3(32, 32, 3), dim3(32, 8), 0, stream>>>(Wq, Wk, Wv, Wt);
    qkv_gemm_k<<<dim3(8, 32, 3), dim3(512), 0, stream>>>(xb, Wt, bq, bk, bv, Qb, Kb, Vb);
    attn_k<<<dim3(32, NH, BATCH), dim3(256), 0, stream>>>(Qb, Kb, Vb, (float*)d_out);
}

// Round 13
// 305.461 us; speedup vs baseline: 1.2415x; 1.0207x over previous
//
#include <hip/hip_runtime.h>
#include <hip/hip_bf16.h>

// MultiheadAttention: x[4,2048,1024] fp32 -> out fp32. Internal bf16 MFMA.
// R13: recombine best-measured variants. attn_k reverted verbatim to R8
// (LD=72 padded tiles, vector staging — R12's unpadded global_load_lds swizzle
// RAISED conflicts 5.5e6->8.1e6 because 128B rows are always bank-aligned).
// gemm stays R11/R12 (256x128, BK=64, global_load_lds).

#define DIM  1024
#define SEQ  2048
#define BATCH 4
#define NH   16
#define HD   64

typedef __bf16 bf16x8 __attribute__((ext_vector_type(8)));
typedef short  s16x4  __attribute__((ext_vector_type(4)));
typedef float  f32x4  __attribute__((ext_vector_type(4)));
typedef unsigned int uint4v __attribute__((ext_vector_type(4)));

static __device__ __forceinline__ f32x4 mfma16(s16x4 a, s16x4 b, f32x4 c) {
    return __builtin_amdgcn_mfma_f32_16x16x16bf16_1k(a, b, c, 0, 0, 0);
}

static __device__ __forceinline__ unsigned short f2b(float f) {
    __bf16 h = (__bf16)f;                      // RNE convert
    return __builtin_bit_cast(unsigned short, h);
}

static __device__ __forceinline__ void load_lds16(const unsigned short* g,
                                                  unsigned short* l) {
    __builtin_amdgcn_global_load_lds(
        (const __attribute__((address_space(1))) void*)g,
        (__attribute__((address_space(3))) void*)l, 16, 0, 0);
}

// ---------------------------------------------------------------------------
// Kernel A: x fp32 -> bf16. 8,388,608 elems -> 4096 blocks.
// ---------------------------------------------------------------------------
__global__ __launch_bounds__(256) void cvt_x_k(const float* __restrict__ x,
                                               unsigned short* __restrict__ xb) {
    size_t i = ((size_t)blockIdx.x * 256 + threadIdx.x) * 8;
    const f32x4* s = (const f32x4*)(x + i);
    f32x4 a0 = s[0], a1 = s[1];
    bf16x8 v;
    for (int j = 0; j < 4; j++) { v[j] = (__bf16)a0[j]; v[4 + j] = (__bf16)a1[j]; }
    *(bf16x8*)(xb + i) = v;
}

// ---------------------------------------------------------------------------
// Kernel 0: Wt[n][k] = bf16(W[k][n]) for z = 0,1,2 (Wq,Wk,Wv). fp32 input.
// ---------------------------------------------------------------------------
__global__ void transpose_w_k(const float* __restrict__ Wq,
                              const float* __restrict__ Wk,
                              const float* __restrict__ Wv,
                              unsigned short* __restrict__ Wt) {
    __shared__ unsigned short t[32][33];
    int z = blockIdx.z;
    const float* W = (z == 0) ? Wq : (z == 1) ? Wk : Wv;
    unsigned short* o = Wt + (size_t)z * DIM * DIM;
    int tx = threadIdx.x;
    int n0 = blockIdx.x * 32, k0 = blockIdx.y * 32;
    for (int j = threadIdx.y; j < 32; j += 8)
        t[j][tx] = f2b(W[(size_t)(k0 + j) * DIM + n0 + tx]);
    __syncthreads();
    for (int j = threadIdx.y; j < 32; j += 8)
        o[(size_t)(n0 + j) * DIM + k0 + tx] = t[tx][j];
}

// ---------------------------------------------------------------------------
// Kernel 1: fused QKV projection (R11/R12, unchanged). grid (8, 32, 3), 512 thr.
// 256x128 tile, BK=64. global_load_lds + XOR swizzle chunk^=(row&7).
// z=0 -> Q scaled log2e/8, z=1 -> K, z=2 -> V^T via per-wave LDS transpose.
// ---------------------------------------------------------------------------
__global__ __launch_bounds__(512) void qkv_gemm_k(
    const unsigned short* __restrict__ xb,
    const unsigned short* __restrict__ WtBase,
    const float* __restrict__ bq,
    const float* __restrict__ bk,
    const float* __restrict__ bv,
    unsigned short* __restrict__ Qo,
    unsigned short* __restrict__ Ko,
    unsigned short* __restrict__ Vto) {
    __shared__ __align__(16) unsigned short As[256 * 64];   // 32 KB, NO pad
    __shared__ __align__(16) unsigned short Bs[128 * 64];   // 16 KB
    int tid = threadIdx.x, wave = tid >> 6, lane = tid & 63;
    int quad = lane >> 4, lc = lane & 15;
    int m0 = blockIdx.y * 256, n0 = blockIdx.x * 128;
    int z = blockIdx.z;
    const unsigned short* Wt = WtBase + (size_t)z * DIM * DIM;
    int wm = (wave >> 1) * 64, wn = (wave & 1) * 64;
    int swzlo = lc & 7;

    f32x4 acc[4][4] = {};

    for (int k0 = 0; k0 < DIM; k0 += 64) {
        __syncthreads();
        #pragma unroll
        for (int p = 0; p < 4; p++) {
            int c = tid + p * 512, r = c >> 3, cc = (c & 7) ^ (r & 7);
            load_lds16(xb + (size_t)(m0 + r) * DIM + k0 + cc * 8, &As[c * 8]);
        }
        #pragma unroll
        for (int p = 0; p < 2; p++) {
            int c = tid + p * 512, r = c >> 3, cc = (c & 7) ^ (r & 7);
            load_lds16(Wt + (size_t)(n0 + r) * DIM + k0 + cc * 8, &Bs[c * 8]);
        }
        __syncthreads();
        #pragma unroll
        for (int kk = 0; kk < 2; kk++) {
            int off = ((kk * 4 + quad) ^ swzlo) * 8;
            bf16x8 af[4], bfr[4];
            for (int mt = 0; mt < 4; mt++)
                af[mt] = *(const bf16x8*)&As[(wm + mt * 16 + lc) * 64 + off];
            for (int nt = 0; nt < 4; nt++)
                bfr[nt] = *(const bf16x8*)&Bs[(wn + nt * 16 + lc) * 64 + off];
            for (int mt = 0; mt < 4; mt++)
                for (int nt = 0; nt < 4; nt++)
                    acc[mt][nt] = __builtin_amdgcn_mfma_f32_16x16x32_bf16(
                        af[mt], bfr[nt], acc[mt][nt], 0, 0, 0);
        }
    }

    const float* bias = (z == 0) ? bq : (z == 1) ? bk : bv;
    float scale = (z == 0) ? 0.18033688011112042f : 1.0f;  // (1/8)*log2(e)

    if (z != 2) {
        for (int nt = 0; nt < 4; nt++) {
            int n = n0 + wn + nt * 16 + lc;
            float bvl = bias[n];
            int h = n >> 6, d = n & 63;
            for (int mt = 0; mt < 4; mt++) {
                for (int r = 0; r < 4; r++) {
                    int m = m0 + wm + mt * 16 + quad * 4 + r;
                    int b = m >> 11, s = m & 2047;
                    unsigned short ub = f2b((acc[mt][nt][r] + bvl) * scale);
                    if (z == 0)
                        Qo[((size_t)(b * NH + h) * SEQ + s) * HD + d] = ub;
                    else
                        Ko[((size_t)(b * NH + h) * SEQ + s) * HD + d] = ub;
                }
            }
        }
    } else {
        // V^T: per-wave LDS transpose (16 m x 64 n slices), coalesced stores.
        __syncthreads();
        unsigned short* T = As + wave * 1024;
        int h = (n0 + wn) >> 6;
        int d = lane;
        for (int mt = 0; mt < 4; mt++) {
            for (int nt = 0; nt < 4; nt++) {
                int n = n0 + wn + nt * 16 + lc;
                float bvl = bias[n];
                s16x4 v4;
                for (int r = 0; r < 4; r++)
                    v4[r] = (short)f2b(acc[mt][nt][r] + bvl);
                *(s16x4*)&T[(nt * 16 + lc) * 16 + quad * 4] = v4;
            }
            int s_base = m0 + wm + mt * 16;
            int b = s_base >> 11, sl = s_base & 2047;
            unsigned short* dst =
                Vto + ((size_t)(b * NH + h) * HD + d) * SEQ + sl;
            uint4v t0 = *(const uint4v*)&T[d * 16];
            uint4v t1 = *(const uint4v*)&T[d * 16 + 8];
            *(uint4v*)&dst[0] = t0;
            *(uint4v*)&dst[8] = t1;
        }
    }
}

// ---------------------------------------------------------------------------
// Kernel 2: flash attention (R8 structure, verbatim). grid (32,16,4), 256 thr.
// Wave w: all 64 q x 16 t per 64-key tile. LD=72 padded tiles, vector staging.
// Score C-layout == K=16 PV B-layout -> P register-resident.
// ---------------------------------------------------------------------------
__global__ __launch_bounds__(256) void attn_k(
    const unsigned short* __restrict__ Q,
    const unsigned short* __restrict__ K,
    const unsigned short* __restrict__ Vt,
    float* __restrict__ out) {
    constexpr int LD = 72;   // bf16 tiles: 64 + 8 pad, rows 144B
    __shared__ __align__(16) unsigned short KV[2 * 64 * LD];  // 18432 B
    unsigned short* Ks = KV;
    unsigned short* Vs = KV + 64 * LD;

    int tid = threadIdx.x, wave = tid >> 6, lane = tid & 63;
    int quad = lane >> 4, lc = lane & 15;
    int w16 = wave * 16;
    int b = blockIdx.z, h = blockIdx.y, qt = blockIdx.x;
    int bh = b * NH + h;
    const unsigned short* Qg = Q + ((size_t)bh * SEQ + qt * 64) * HD;
    const unsigned short* Kg = K + (size_t)bh * SEQ * HD;
    const unsigned short* Vg = Vt + (size_t)bh * HD * SEQ;

    for (int p = 0; p < 2; p++) {
        int c = tid + p * 256;
        int row = c >> 3, cc = c & 7;
        *(uint4v*)&Ks[row * LD + cc * 8] = *(const uint4v*)&Qg[c * 8];
    }
    __syncthreads();
    bf16x8 qf[4][2];  // [g][ks]: B[k=d=ks*32+quad*8+j][n=q=g*16+lc]
    #pragma unroll
    for (int g = 0; g < 4; g++)
        #pragma unroll
        for (int ks = 0; ks < 2; ks++)
            qf[g][ks] = *(const bf16x8*)&Ks[(g * 16 + lc) * LD + ks * 32 + quad * 8];

    f32x4 o[4][4] = {};   // [dt][g]: O^T[d=dt*16+quad*4+r][q=g*16+lc]
    float rsum[4] = {};

    for (int t0 = 0; t0 < SEQ; t0 += 64) {
        __syncthreads();
        for (int p = 0; p < 2; p++) {
            int c = tid + p * 256;
            int row = c >> 3, cc = c & 7;
            *(uint4v*)&Ks[row * LD + cc * 8] =
                *(const uint4v*)&Kg[(size_t)t0 * HD + c * 8];
            *(uint4v*)&Vs[row * LD + cc * 8] =
                *(const uint4v*)&Vg[(size_t)row * SEQ + t0 + cc * 8];
        }
        __syncthreads();

        f32x4 sc[4] = {};
        #pragma unroll
        for (int ks = 0; ks < 2; ks++) {
            bf16x8 kf = *(const bf16x8*)&Ks[(w16 + lc) * LD + ks * 32 + quad * 8];
            #pragma unroll
            for (int g = 0; g < 4; g++)
                sc[g] = __builtin_amdgcn_mfma_f32_16x16x32_bf16(
                    kf, qf[g][ks], sc[g], 0, 0, 0);
        }

        s16x4 pf[4];
        #pragma unroll
        for (int g = 0; g < 4; g++) {
            float p0 = __builtin_amdgcn_exp2f(sc[g][0]);
            float p1 = __builtin_amdgcn_exp2f(sc[g][1]);
            float p2 = __builtin_amdgcn_exp2f(sc[g][2]);
            float p3 = __builtin_amdgcn_exp2f(sc[g][3]);
            rsum[g] += (p0 + p1) + (p2 + p3);
            pf[g][0] = (short)f2b(p0); pf[g][1] = (short)f2b(p1);
            pf[g][2] = (short)f2b(p2); pf[g][3] = (short)f2b(p3);
        }

        #pragma unroll
        for (int dt = 0; dt < 4; dt++) {
            s16x4 vf = *(const s16x4*)&Vs[(dt * 16 + lc) * LD + w16 + quad * 4];
            #pragma unroll
            for (int g = 0; g < 4; g++)
                o[dt][g] = mfma16(vf, pf[g], o[dt][g]);
        }
    }

    #pragma unroll
    for (int g = 0; g < 4; g++) {
        rsum[g] += __shfl_xor(rsum[g], 16);
        rsum[g] += __shfl_xor(rsum[g], 32);
    }

    __syncthreads();
    float* OredF = (float*)KV;            // [4w][64q][16dd] = 16384 B
    float* rsArr = (float*)KV + 4096;     // [4w][64q] = 1024 B
    if (lane < 16)
        #pragma unroll
        for (int g = 0; g < 4; g++)
            rsArr[wave * 64 + g * 16 + lane] = rsum[g];

    int q = tid >> 2, cs = tid & 3;
    float inv = 0.0f;
    float* orow = out + ((size_t)b * SEQ + qt * 64 + q) * DIM + h * HD;
    #pragma unroll
    for (int dt = 0; dt < 4; dt++) {
        #pragma unroll
        for (int g = 0; g < 4; g++)
            *(f32x4*)&OredF[wave * 1024 + (g * 16 + lc) * 16 + quad * 4] = o[dt][g];
        __syncthreads();
        if (dt == 0)
            inv = 1.0f / (rsArr[q] + rsArr[64 + q] + rsArr[128 + q] + rsArr[192 + q]);
        f32x4 s = *(const f32x4*)&OredF[q * 16 + cs * 4];
        #pragma unroll
        for (int w = 1; w < 4; w++)
            s += *(const f32x4*)&OredF[w * 1024 + q * 16 + cs * 4];
        s *= inv;
        *(f32x4*)&orow[dt * 16 + cs * 4] = s;
        __syncthreads();
    }
}

// ---------------------------------------------------------------------------
extern "C" void kernel_launch(void* const* d_in, const int* in_sizes, int n_in,
                              void* d_out, int out_size, void* d_ws, size_t ws_size,
                              hipStream_t stream) {
    (void)in_sizes; (void)n_in; (void)out_size; (void)ws_size;
    const float* x  = (const float*)d_in[0];
    const float* Wq = (const float*)d_in[1];
    const float* bq = (const float*)d_in[2];
    const float* Wk = (const float*)d_in[3];
    const float* bk = (const float*)d_in[4];
    const float* Wv = (const float*)d_in[5];
    const float* bv = (const float*)d_in[6];

    char* ws = (char*)d_ws;
    unsigned short* Wt = (unsigned short*)ws;                             // 6 MB
    unsigned short* Qb = (unsigned short*)(ws + (size_t)6 * 1024 * 1024);
    unsigned short* Kb = Qb + (size_t)BATCH * NH * SEQ * HD;
    unsigned short* Vb = Kb + (size_t)BATCH * NH * SEQ * HD;
    unsigned short* xb = (unsigned short*)d_out;  // scratch; attn overwrites

    cvt_x_k<<<dim3(4096), dim3(256), 0, stream>>>(x, xb);
    transpose_w_k<<<dim3(32, 32, 3), dim3(32, 8), 0, stream>>>(Wq, Wk, Wv, Wt);
    qkv_gemm_k<<<dim3(8, 32, 3), dim3(512), 0, stream>>>(xb, Wt, bq, bk, bv, Qb, Kb, Vb);
    attn_k<<<dim3(32, NH, BATCH), dim3(256), 0, stream>>>(Qb, Kb, Vb, (float*)d_out);
}